// Round 20
// baseline (172.699 us; speedup 1.0000x reference)
//
#include <hip/hip_runtime.h>
#include <hip/hip_fp16.h>
#include <hip/hip_fp8.h>

#define N_NODES 100000
#define N_EDGES 3200000
#define F_IN    61
#define F_HID   16
#define F_OUT   2
#define HB      256                    // edge chunks
#define CHUNK   (N_EDGES / HB)         // 12500
#define BSIZE   512                    // nodes per dst-bucket
#define NBUCK   196                    // ceil(N_NODES / BSIZE)
#define RPT     17                     // fscatter reg-staged entries/thread
#define FCAP    (1024 * RPT)           // 17408 >= seg mean 16327 + 8 sigma

typedef unsigned int uint;

// Edge record (u32, buck AND vals): [31:15] src, [14:6] dst_local, [5:0] u_q6.
// hp8 table: fp8 e4m3, 32 B/node (16 feat x 2 knots) -> 3.2 MB, fits 4 MB L2.

// ---------------- layer-1 node transforms ----------------
// 4 lanes per node; fp8-encodes h via __hip_fp8x4_e4m3; r1 stays f32.
__global__ __launch_bounds__(256) void k_transform1(
    const float* __restrict__ x, const float* __restrict__ W1,
    const float* __restrict__ root1, const float* __restrict__ b1,
    uint2* __restrict__ hp8, float* __restrict__ r1)
{
    __shared__ float w0s[F_IN * F_HID];
    __shared__ float w1s[F_IN * F_HID];
    __shared__ float rs [F_IN * F_HID];
    __shared__ float bs [F_HID];

    const int tid = threadIdx.x;
    for (int i = tid; i < F_IN * F_HID; i += 256) {
        w0s[i] = W1[i];
        w1s[i] = W1[F_IN * F_HID + i];
        rs[i]  = root1[i];
    }
    if (tid < F_HID) bs[tid] = b1[tid];
    __syncthreads();

    const int j = tid & 3;
    const int n = (blockIdx.x * 256 + tid) >> 2;
    if (n >= N_NODES) return;

    float a0[F_HID], a1[F_HID], ar[F_HID];
    #pragma unroll
    for (int c = 0; c < F_HID; ++c) { a0[c] = 0.f; a1[c] = 0.f; ar[c] = 0.f; }

    const float* xr = x + (size_t)n * F_IN;
    for (int f = j; f < F_IN; f += 4) {
        const float xv = xr[f];
        #pragma unroll
        for (int c = 0; c < F_HID; ++c) {
            a0[c] = fmaf(xv, w0s[f * F_HID + c], a0[c]);
            a1[c] = fmaf(xv, w1s[f * F_HID + c], a1[c]);
            ar[c] = fmaf(xv, rs [f * F_HID + c], ar[c]);
        }
    }

    #pragma unroll
    for (int c = 0; c < F_HID; ++c) {
        a0[c] += __shfl_xor(a0[c], 1); a0[c] += __shfl_xor(a0[c], 2);
        a1[c] += __shfl_xor(a1[c], 1); a1[c] += __shfl_xor(a1[c], 2);
        ar[c] += __shfl_xor(ar[c], 1); ar[c] += __shfl_xor(ar[c], 2);
    }

    // lane j encodes features 4j..4j+3 as two fp8x4 words:
    //   word0 = (h0[c], h1[c], h0[c+1], h1[c+1]) for c = 4j; word1 for c=4j+2
    const int c0 = 4 * j;
    __hip_fp8x4_e4m3 p0(make_float4(a0[c0 + 0], a1[c0 + 0], a0[c0 + 1], a1[c0 + 1]));
    __hip_fp8x4_e4m3 p1(make_float4(a0[c0 + 2], a1[c0 + 2], a0[c0 + 3], a1[c0 + 3]));
    uint2 w;
    w.x = (uint)p0.__x;
    w.y = (uint)p1.__x;
    hp8[(size_t)n * 4 + j] = w;

    float4 rv = make_float4(ar[c0 + 0] + bs[c0 + 0], ar[c0 + 1] + bs[c0 + 1],
                            ar[c0 + 2] + bs[c0 + 2], ar[c0 + 3] + bs[c0 + 3]);
    ((float4*)r1)[(size_t)n * 4 + j] = rv;
}

// ---------------- phase A: per-(chunk,bucket) counts; 2 sub-bins -----------
__global__ __launch_bounds__(1024) void k_bhist(
    const int* __restrict__ edst, uint* __restrict__ cnt)
{
    __shared__ uint bins[2][NBUCK];
    uint* fb = &bins[0][0];
    const int bx = blockIdx.x, tid = threadIdx.x;
    for (int i = tid; i < 2 * NBUCK; i += 1024) fb[i] = 0;
    __syncthreads();
    const int e0 = bx * CHUNK, e1 = e0 + CHUNK;
    const int sb = tid & 1;
    for (int e = e0 + tid; e < e1; e += 1024)
        atomicAdd(&bins[sb][((uint)edst[e]) >> 9], 1u);
    __syncthreads();
    for (int i = tid; i < NBUCK; i += 1024)
        cnt[(size_t)i * HB + bx] = bins[0][i] + bins[1][i];
}

// ---- scan 1: per-bucket LDS scan over its chunk row; emit bucket total ----
__global__ __launch_bounds__(256) void k_brow1(
    uint* __restrict__ cnt, uint* __restrict__ tot)
{
    __shared__ uint s[256];
    const int b = blockIdx.x, tid = threadIdx.x;   // HB == 256
    const uint v = cnt[(size_t)b * HB + tid];
    s[tid] = v; __syncthreads();
    for (int off = 1; off < 256; off <<= 1) {
        const uint t = (tid >= off) ? s[tid - off] : 0u;
        __syncthreads();
        s[tid] += t;
        __syncthreads();
    }
    cnt[(size_t)b * HB + tid] = s[tid] - v;        // exclusive within bucket
    if (tid == 255) tot[b] = s[255];
}

// ---- scan 2: exclusive scan of bucket totals -> bstart --------------------
__global__ __launch_bounds__(256) void k_bexc(
    const uint* __restrict__ tot, uint* __restrict__ bstart)
{
    __shared__ uint s[256];
    const int tid = threadIdx.x;
    const uint v = (tid < NBUCK) ? tot[tid] : 0u;
    s[tid] = v; __syncthreads();
    for (int off = 1; off < 256; off <<= 1) {
        const uint t = (tid >= off) ? s[tid - off] : 0u;
        __syncthreads();
        s[tid] += t;
        __syncthreads();
    }
    if (tid < NBUCK) bstart[tid] = s[tid] - v;
    if (tid == 0) bstart[NBUCK] = N_EDGES;
}

// ---- phase A scatter: append packed u32 records to bucket streams ---------
__global__ __launch_bounds__(1024) void k_bscatter(
    const int* __restrict__ esrc, const int* __restrict__ edst,
    const float* __restrict__ attr, const uint* __restrict__ cnt,
    const uint* __restrict__ bstart, uint* __restrict__ buck)
{
    __shared__ uint pos[NBUCK];
    const int bx = blockIdx.x, tid = threadIdx.x;
    for (int i = tid; i < NBUCK; i += 1024)
        pos[i] = cnt[(size_t)i * HB + bx] + bstart[i];
    __syncthreads();
    const int e0 = bx * CHUNK, e1 = e0 + CHUNK;
    for (int e = e0 + tid; e < e1; e += 1024) {
        const uint d = (uint)edst[e];
        const uint uq = (uint)(attr[e] * 63.0f + 0.5f);
        const uint p = atomicAdd(&pos[d >> 9], 1u);
        buck[p] = ((uint)esrc[e] << 15) | ((d & 511u) << 6) | uq;
    }
}

// ---- phase B: reg-staged per-bucket count+scan -> rowptr, dense scatter ---
__global__ __launch_bounds__(1024) void k_fscatter(
    const uint* __restrict__ buck, const uint* __restrict__ bstart,
    uint* __restrict__ rowptr, uint* __restrict__ vals)
{
    __shared__ uint deg[BSIZE];     // then running positions
    __shared__ uint excl[BSIZE];
    const int b = blockIdx.x, tid = threadIdx.x;
    const uint e0 = bstart[b], e1 = bstart[b + 1];
    const bool fits = (e1 - e0) <= (uint)FCAP;

    for (int i = tid; i < BSIZE; i += 1024) deg[i] = 0;
    __syncthreads();

    uint r[RPT];
    if (fits) {
        #pragma unroll
        for (int k = 0; k < RPT; ++k) {
            const uint e = e0 + (uint)tid + (uint)k * 1024u;
            if (e < e1) r[k] = buck[e];
        }
        #pragma unroll
        for (int k = 0; k < RPT; ++k) {
            const uint e = e0 + (uint)tid + (uint)k * 1024u;
            if (e < e1) atomicAdd(&deg[(r[k] >> 6) & 511u], 1u);
        }
    } else {
        for (uint e = e0 + tid; e < e1; e += 1024)
            atomicAdd(&deg[(buck[e] >> 6) & 511u], 1u);
    }
    __syncthreads();

    if (tid < BSIZE) excl[tid] = deg[tid];
    __syncthreads();
    for (int off = 1; off < BSIZE; off <<= 1) {
        uint t = 0;
        if (tid < BSIZE && tid >= off) t = excl[tid - off];
        __syncthreads();
        if (tid < BSIZE) excl[tid] += t;
        __syncthreads();
    }
    if (tid < BSIZE) {
        const uint ex = excl[tid] - deg[tid];   // exclusive prefix
        const int n = b * BSIZE + tid;
        if (n < N_NODES) rowptr[n] = e0 + ex;
        deg[tid] = ex;                          // reuse as running position
    }
    if (b == 0 && tid == 0) rowptr[N_NODES] = N_EDGES;
    __syncthreads();

    if (fits) {
        #pragma unroll
        for (int k = 0; k < RPT; ++k) {
            const uint e = e0 + (uint)tid + (uint)k * 1024u;
            if (e < e1) {
                const uint p = atomicAdd(&deg[(r[k] >> 6) & 511u], 1u);
                vals[e0 + p] = r[k];
            }
        }
    } else {
        for (uint e = e0 + tid; e < e1; e += 1024) {
            const uint w = buck[e];
            const uint p = atomicAdd(&deg[(w >> 6) & 511u], 1u);
            vals[e0 + p] = w;
        }
    }
}

// ---------------- FUSED layer-1 aggregate + finalize -----------------------
// wave per node; lanes = 16 edge-slots x 4 feature-quads. Each lane fetches
// 8 B fp8 (features 4q..4q+3, both knots) from the L2-resident table, f32
// accumulates, slot-butterfly, then in-wave mean+ELU+layer-2 transform
// (deletes k_mid2 and the sum1 round-trip).
__global__ __launch_bounds__(256) void k_agg1(
    const uint* __restrict__ rowptr, const uint* __restrict__ vals,
    const uint2* __restrict__ hp8, const float4* __restrict__ r1v4,
    const float* __restrict__ W2, const float* __restrict__ root2,
    const float* __restrict__ b2,
    float4* __restrict__ h2, float2* __restrict__ r2)
{
    __shared__ uint2 ent[4][64];        // 2 KB: per-wave {src, u_bits}
    __shared__ float w2s[2 * F_HID * F_OUT];
    __shared__ float rts[F_HID * F_OUT];
    __shared__ float b2s[F_OUT];
    const int tid = threadIdx.x;
    if (tid < 2 * F_HID * F_OUT) w2s[tid] = W2[tid];
    if (tid < F_HID * F_OUT)     rts[tid] = root2[tid];
    if (tid < F_OUT)             b2s[tid] = b2[tid];

    const int lane = tid & 63;
    const int wave = tid >> 6;
    const int n = blockIdx.x * 4 + wave;
    const int ep = lane >> 2;          // edge slot 0..15
    const int q  = lane & 3;           // feature quad: features 4q..4q+3

    const uint r0 = rowptr[n];
    const uint deg = rowptr[n + 1] - r0;
    const uint dcap = min(deg, 64u);

    if ((uint)lane < dcap) {
        const uint v = __builtin_nontemporal_load(&vals[r0 + lane]);
        const float uu = (float)(v & 63u) * (1.0f / 63.0f);
        ent[wave][lane] = make_uint2(v >> 15, __float_as_uint(uu));
    }
    __syncthreads();            // covers ent AND w2s/rts/b2s

    float4 acc = make_float4(0.f, 0.f, 0.f, 0.f);
    #pragma unroll 2
    for (uint i = ep; i < dcap; i += 16) {
        const uint2 e = ent[wave][i];
        const float u = __uint_as_float(e.y);
        const float w0 = 1.0f - u;
        const uint2 hw = hp8[(size_t)e.x * 4 + q];
        __hip_fp8x4_e4m3 p0, p1;
        p0.__x = (__hip_fp8x4_storage_t)hw.x;
        p1.__x = (__hip_fp8x4_storage_t)hw.y;
        const float4 f0 = (float4)p0;   // (h0_c, h1_c, h0_c+1, h1_c+1), c=4q
        const float4 f1 = (float4)p1;   // c = 4q+2
        acc.x += w0 * f0.x + u * f0.y;
        acc.y += w0 * f0.z + u * f0.w;
        acc.z += w0 * f1.x + u * f1.y;
        acc.w += w0 * f1.z + u * f1.w;
    }
    for (uint i = 64 + ep; i < deg; i += 16) {   // rare overflow tail
        const uint v = __builtin_nontemporal_load(&vals[r0 + i]);
        const float u = (float)(v & 63u) * (1.0f / 63.0f);
        const float w0 = 1.0f - u;
        const uint2 hw = hp8[(size_t)(v >> 15) * 4 + q];
        __hip_fp8x4_e4m3 p0, p1;
        p0.__x = (__hip_fp8x4_storage_t)hw.x;
        p1.__x = (__hip_fp8x4_storage_t)hw.y;
        const float4 f0 = (float4)p0;
        const float4 f1 = (float4)p1;
        acc.x += w0 * f0.x + u * f0.y;
        acc.y += w0 * f0.z + u * f0.w;
        acc.z += w0 * f1.x + u * f1.y;
        acc.w += w0 * f1.z + u * f1.w;
    }

    // butterfly over the 16 edge slots (lane bits 2..5); all lanes uniform
    #pragma unroll
    for (int off = 4; off <= 32; off <<= 1) {
        acc.x += __shfl_xor(acc.x, off);
        acc.y += __shfl_xor(acc.y, off);
        acc.z += __shfl_xor(acc.z, off);
        acc.w += __shfl_xor(acc.w, off);
    }

    // ---- in-wave finalize: mean + ELU + layer-2 transforms ----
    const float inv = 1.0f / (float)max(deg, 1u);
    const float4 rv = r1v4[(size_t)n * 4 + q];
    float h0 = acc.x * inv + rv.x; h0 = (h0 > 0.f) ? h0 : expm1f(h0);
    float h1 = acc.y * inv + rv.y; h1 = (h1 > 0.f) ? h1 : expm1f(h1);
    float hc2 = acc.z * inv + rv.z; hc2 = (hc2 > 0.f) ? hc2 : expm1f(hc2);
    float h3 = acc.w * inv + rv.w; h3 = (h3 > 0.f) ? h3 : expm1f(h3);

    const int c0 = 4 * q;
    float o00 = 0.f, o01 = 0.f, o10 = 0.f, o11 = 0.f, rr0 = 0.f, rr1 = 0.f;
    const float hh[4] = {h0, h1, hc2, h3};
    #pragma unroll
    for (int k = 0; k < 4; ++k) {
        const int c = c0 + k;
        o00 = fmaf(hh[k], w2s[c * 2 + 0], o00);
        o01 = fmaf(hh[k], w2s[c * 2 + 1], o01);
        o10 = fmaf(hh[k], w2s[2 * F_HID + c * 2 + 0], o10);
        o11 = fmaf(hh[k], w2s[2 * F_HID + c * 2 + 1], o11);
        rr0 = fmaf(hh[k], rts[c * 2 + 0], rr0);
        rr1 = fmaf(hh[k], rts[c * 2 + 1], rr1);
    }
    #pragma unroll
    for (int off = 1; off <= 2; off <<= 1) {
        o00 += __shfl_xor(o00, off); o01 += __shfl_xor(o01, off);
        o10 += __shfl_xor(o10, off); o11 += __shfl_xor(o11, off);
        rr0 += __shfl_xor(rr0, off); rr1 += __shfl_xor(rr1, off);
    }
    if (lane == 0) {
        h2[n] = make_float4(o00, o10, o01, o11);   // (k0o0, k1o0, k0o1, k1o1)
        r2[n] = make_float2(rr0 + b2s[0], rr1 + b2s[1]);
    }
}

// ---------------- layer-2 pull aggregate + log_softmax --------------------
// 2 nodes per wave; 1 lane per edge; no LDS.
__global__ __launch_bounds__(256) void k_agg2(
    const uint* __restrict__ rowptr, const uint* __restrict__ vals,
    const float4* __restrict__ h2, const float2* __restrict__ r2,
    float2* __restrict__ out)
{
    const int tid  = threadIdx.x;
    const int lane = tid & 63;
    const int wave = tid >> 6;
    const int half = lane & 31;
    const int n = blockIdx.x * 8 + wave * 2 + (lane >> 5);

    const uint r0 = rowptr[n];
    const uint deg = rowptr[n + 1] - r0;

    float acc0 = 0.f, acc1 = 0.f;
    for (uint i = half; i < deg; i += 32) {
        const uint v = __builtin_nontemporal_load(&vals[r0 + i]);
        const float uu = (float)(v & 63u) * (1.0f / 63.0f);
        const float4 h = h2[v >> 15];
        acc0 += (1.0f - uu) * h.x + uu * h.y;   // out0: (1-u)*k0 + u*k1
        acc1 += (1.0f - uu) * h.z + uu * h.w;   // out1
    }
    #pragma unroll
    for (int off = 1; off <= 16; off <<= 1) {
        acc0 += __shfl_xor(acc0, off);
        acc1 += __shfl_xor(acc1, off);
    }

    if (half == 0) {
        const float inv = 1.0f / (float)max(deg, 1u);
        const float2 rr = r2[n];
        const float o0 = acc0 * inv + rr.x;
        const float o1 = acc1 * inv + rr.y;
        const float m  = fmaxf(o0, o1);
        const float l  = m + logf(expf(o0 - m) + expf(o1 - m));
        out[n] = make_float2(o0 - l, o1 - l);
    }
}

extern "C" void kernel_launch(void* const* d_in, const int* in_sizes, int n_in,
                              void* d_out, int out_size, void* d_ws, size_t ws_size,
                              hipStream_t stream) {
    const float* x     = (const float*)d_in[0];
    const int*   ei    = (const int*)  d_in[1];   // [2][N_EDGES]
    const float* attr  = (const float*)d_in[2];
    const float* W1    = (const float*)d_in[4];
    const float* root1 = (const float*)d_in[5];
    const float* b1    = (const float*)d_in[6];
    const float* W2    = (const float*)d_in[7];
    const float* root2 = (const float*)d_in[8];
    const float* b2    = (const float*)d_in[9];
    float2* out = (float2*)d_out;

    char* ws = (char*)d_ws;
    size_t off = 0;
    uint*  vals   = (uint*) (ws + off); off += (size_t)N_EDGES * sizeof(uint);         // 12.8MB
    uint*  rowptr = (uint*) (ws + off); off += (size_t)(N_NODES + 1) * sizeof(uint);
    uint*  cnt    = (uint*) (ws + off); off += (size_t)NBUCK * HB * sizeof(uint);      // 200KB
    uint*  bstart = (uint*) (ws + off); off += (size_t)(NBUCK + 1) * sizeof(uint);
    uint*  tot    = (uint*) (ws + off); off += (size_t)NBUCK * sizeof(uint);
    off = (off + 255) & ~(size_t)255;
    uint*  buck   = (uint*) (ws + off); off += (size_t)N_EDGES * sizeof(uint);         // 12.8MB

    // buck is dead after k_fscatter; node buffers alias from buck onward.
    char* alias = (char*)buck;
    size_t aoff = 0;
    uint2*  hp8 = (uint2*) (alias + aoff); aoff += (size_t)N_NODES * 4 * sizeof(uint2);       // 3.2MB
    float*   r1 = (float*) (alias + aoff); aoff += (size_t)N_NODES * F_HID * sizeof(float);   // 6.4MB
    float4*  h2 = (float4*)(alias + aoff); aoff += (size_t)N_NODES * sizeof(float4);          // 1.6MB
    float2*  r2 = (float2*)(alias + aoff); aoff += (size_t)N_NODES * sizeof(float2);          // 0.8MB
    (void)ws_size;

    const int* esrc = ei;
    const int* edst = ei + N_EDGES;

    k_bhist    <<<HB, 1024, 0, stream>>>(edst, cnt);
    k_brow1    <<<NBUCK, 256, 0, stream>>>(cnt, tot);
    k_bexc     <<<1, 256, 0, stream>>>(tot, bstart);
    k_bscatter <<<HB, 1024, 0, stream>>>(esrc, edst, attr, cnt, bstart, buck);
    k_fscatter <<<NBUCK, 1024, 0, stream>>>(buck, bstart, rowptr, vals);
    k_transform1<<<(N_NODES * 4 + 255) / 256, 256, 0, stream>>>(x, W1, root1, b1, hp8, r1);
    k_agg1     <<<N_NODES / 4, 256, 0, stream>>>(rowptr, vals, hp8, (const float4*)r1,
                                                 W2, root2, b2, h2, r2);
    k_agg2     <<<N_NODES / 8, 256, 0, stream>>>(rowptr, vals, h2, r2, out);
}

// Round 21
// 164.020 us; speedup vs baseline: 1.0529x; 1.0529x over previous
//
#include <hip/hip_runtime.h>
#include <hip/hip_fp16.h>
#include <hip/hip_fp8.h>

#define N_NODES 100000
#define N_EDGES 3200000
#define F_IN    61
#define F_HID   16
#define F_OUT   2
#define HB      256                    // edge chunks
#define CHUNK   (N_EDGES / HB)         // 12500
#define BSIZE   512                    // nodes per dst-bucket
#define NBUCK   196                    // ceil(N_NODES / BSIZE)
#define RPT     17                     // fscatter reg-staged entries/thread
#define FCAP    (1024 * RPT)           // 17408 >= seg mean 16327 + 8 sigma

typedef unsigned int uint;

// Edge record (u32, buck AND vals): [31:15] src, [14:6] dst_local, [5:0] u_q6.
// hp8 table: fp8 e4m3, 32 B/node (16 feat x 2 knots) -> 3.2 MB, fits 4 MB L2.
// This is the round-19 configuration (measured 164 µs) — round-20's 4-lane
// fusion regressed to VALU-bound (80% VALUBusy) and was reverted.

// ---------------- layer-1 node transforms ----------------
// 4 lanes per node; fp8-encodes h via __hip_fp8x4_e4m3; r1 stays f32.
__global__ __launch_bounds__(256) void k_transform1(
    const float* __restrict__ x, const float* __restrict__ W1,
    const float* __restrict__ root1, const float* __restrict__ b1,
    uint2* __restrict__ hp8, float* __restrict__ r1)
{
    __shared__ float w0s[F_IN * F_HID];
    __shared__ float w1s[F_IN * F_HID];
    __shared__ float rs [F_IN * F_HID];
    __shared__ float bs [F_HID];

    const int tid = threadIdx.x;
    for (int i = tid; i < F_IN * F_HID; i += 256) {
        w0s[i] = W1[i];
        w1s[i] = W1[F_IN * F_HID + i];
        rs[i]  = root1[i];
    }
    if (tid < F_HID) bs[tid] = b1[tid];
    __syncthreads();

    const int j = tid & 3;
    const int n = (blockIdx.x * 256 + tid) >> 2;
    if (n >= N_NODES) return;

    float a0[F_HID], a1[F_HID], ar[F_HID];
    #pragma unroll
    for (int c = 0; c < F_HID; ++c) { a0[c] = 0.f; a1[c] = 0.f; ar[c] = 0.f; }

    const float* xr = x + (size_t)n * F_IN;
    for (int f = j; f < F_IN; f += 4) {
        const float xv = xr[f];
        #pragma unroll
        for (int c = 0; c < F_HID; ++c) {
            a0[c] = fmaf(xv, w0s[f * F_HID + c], a0[c]);
            a1[c] = fmaf(xv, w1s[f * F_HID + c], a1[c]);
            ar[c] = fmaf(xv, rs [f * F_HID + c], ar[c]);
        }
    }

    #pragma unroll
    for (int c = 0; c < F_HID; ++c) {
        a0[c] += __shfl_xor(a0[c], 1); a0[c] += __shfl_xor(a0[c], 2);
        a1[c] += __shfl_xor(a1[c], 1); a1[c] += __shfl_xor(a1[c], 2);
        ar[c] += __shfl_xor(ar[c], 1); ar[c] += __shfl_xor(ar[c], 2);
    }

    // lane j encodes features 4j..4j+3 as two fp8x4 words:
    //   word0 = (h0[c], h1[c], h0[c+1], h1[c+1]) for c = 4j; word1 for c=4j+2
    const int c0 = 4 * j;
    __hip_fp8x4_e4m3 p0(make_float4(a0[c0 + 0], a1[c0 + 0], a0[c0 + 1], a1[c0 + 1]));
    __hip_fp8x4_e4m3 p1(make_float4(a0[c0 + 2], a1[c0 + 2], a0[c0 + 3], a1[c0 + 3]));
    uint2 w;
    w.x = (uint)p0.__x;
    w.y = (uint)p1.__x;
    hp8[(size_t)n * 4 + j] = w;

    float4 rv = make_float4(ar[c0 + 0] + bs[c0 + 0], ar[c0 + 1] + bs[c0 + 1],
                            ar[c0 + 2] + bs[c0 + 2], ar[c0 + 3] + bs[c0 + 3]);
    ((float4*)r1)[(size_t)n * 4 + j] = rv;
}

// ---------------- phase A: per-(chunk,bucket) counts; 2 sub-bins -----------
__global__ __launch_bounds__(1024) void k_bhist(
    const int* __restrict__ edst, uint* __restrict__ cnt)
{
    __shared__ uint bins[2][NBUCK];
    uint* fb = &bins[0][0];
    const int bx = blockIdx.x, tid = threadIdx.x;
    for (int i = tid; i < 2 * NBUCK; i += 1024) fb[i] = 0;
    __syncthreads();
    const int e0 = bx * CHUNK, e1 = e0 + CHUNK;
    const int sb = tid & 1;
    for (int e = e0 + tid; e < e1; e += 1024)
        atomicAdd(&bins[sb][((uint)edst[e]) >> 9], 1u);
    __syncthreads();
    for (int i = tid; i < NBUCK; i += 1024)
        cnt[(size_t)i * HB + bx] = bins[0][i] + bins[1][i];
}

// ---- scan 1: per-bucket LDS scan over its chunk row; emit bucket total ----
__global__ __launch_bounds__(256) void k_brow1(
    uint* __restrict__ cnt, uint* __restrict__ tot)
{
    __shared__ uint s[256];
    const int b = blockIdx.x, tid = threadIdx.x;   // HB == 256
    const uint v = cnt[(size_t)b * HB + tid];
    s[tid] = v; __syncthreads();
    for (int off = 1; off < 256; off <<= 1) {
        const uint t = (tid >= off) ? s[tid - off] : 0u;
        __syncthreads();
        s[tid] += t;
        __syncthreads();
    }
    cnt[(size_t)b * HB + tid] = s[tid] - v;        // exclusive within bucket
    if (tid == 255) tot[b] = s[255];
}

// ---- scan 2: exclusive scan of bucket totals -> bstart --------------------
__global__ __launch_bounds__(256) void k_bexc(
    const uint* __restrict__ tot, uint* __restrict__ bstart)
{
    __shared__ uint s[256];
    const int tid = threadIdx.x;
    const uint v = (tid < NBUCK) ? tot[tid] : 0u;
    s[tid] = v; __syncthreads();
    for (int off = 1; off < 256; off <<= 1) {
        const uint t = (tid >= off) ? s[tid - off] : 0u;
        __syncthreads();
        s[tid] += t;
        __syncthreads();
    }
    if (tid < NBUCK) bstart[tid] = s[tid] - v;
    if (tid == 0) bstart[NBUCK] = N_EDGES;
}

// ---- phase A scatter: append packed u32 records to bucket streams ---------
__global__ __launch_bounds__(1024) void k_bscatter(
    const int* __restrict__ esrc, const int* __restrict__ edst,
    const float* __restrict__ attr, const uint* __restrict__ cnt,
    const uint* __restrict__ bstart, uint* __restrict__ buck)
{
    __shared__ uint pos[NBUCK];
    const int bx = blockIdx.x, tid = threadIdx.x;
    for (int i = tid; i < NBUCK; i += 1024)
        pos[i] = cnt[(size_t)i * HB + bx] + bstart[i];
    __syncthreads();
    const int e0 = bx * CHUNK, e1 = e0 + CHUNK;
    for (int e = e0 + tid; e < e1; e += 1024) {
        const uint d = (uint)edst[e];
        const uint uq = (uint)(attr[e] * 63.0f + 0.5f);
        const uint p = atomicAdd(&pos[d >> 9], 1u);
        buck[p] = ((uint)esrc[e] << 15) | ((d & 511u) << 6) | uq;
    }
}

// ---- phase B: reg-staged per-bucket count+scan -> rowptr, dense scatter ---
__global__ __launch_bounds__(1024) void k_fscatter(
    const uint* __restrict__ buck, const uint* __restrict__ bstart,
    uint* __restrict__ rowptr, uint* __restrict__ vals)
{
    __shared__ uint deg[BSIZE];     // then running positions
    __shared__ uint excl[BSIZE];
    const int b = blockIdx.x, tid = threadIdx.x;
    const uint e0 = bstart[b], e1 = bstart[b + 1];
    const bool fits = (e1 - e0) <= (uint)FCAP;

    for (int i = tid; i < BSIZE; i += 1024) deg[i] = 0;
    __syncthreads();

    uint r[RPT];
    if (fits) {
        #pragma unroll
        for (int k = 0; k < RPT; ++k) {
            const uint e = e0 + (uint)tid + (uint)k * 1024u;
            if (e < e1) r[k] = buck[e];
        }
        #pragma unroll
        for (int k = 0; k < RPT; ++k) {
            const uint e = e0 + (uint)tid + (uint)k * 1024u;
            if (e < e1) atomicAdd(&deg[(r[k] >> 6) & 511u], 1u);
        }
    } else {
        for (uint e = e0 + tid; e < e1; e += 1024)
            atomicAdd(&deg[(buck[e] >> 6) & 511u], 1u);
    }
    __syncthreads();

    if (tid < BSIZE) excl[tid] = deg[tid];
    __syncthreads();
    for (int off = 1; off < BSIZE; off <<= 1) {
        uint t = 0;
        if (tid < BSIZE && tid >= off) t = excl[tid - off];
        __syncthreads();
        if (tid < BSIZE) excl[tid] += t;
        __syncthreads();
    }
    if (tid < BSIZE) {
        const uint ex = excl[tid] - deg[tid];   // exclusive prefix
        const int n = b * BSIZE + tid;
        if (n < N_NODES) rowptr[n] = e0 + ex;
        deg[tid] = ex;                          // reuse as running position
    }
    if (b == 0 && tid == 0) rowptr[N_NODES] = N_EDGES;
    __syncthreads();

    if (fits) {
        #pragma unroll
        for (int k = 0; k < RPT; ++k) {
            const uint e = e0 + (uint)tid + (uint)k * 1024u;
            if (e < e1) {
                const uint p = atomicAdd(&deg[(r[k] >> 6) & 511u], 1u);
                vals[e0 + p] = r[k];
            }
        }
    } else {
        for (uint e = e0 + tid; e < e1; e += 1024) {
            const uint w = buck[e];
            const uint p = atomicAdd(&deg[(w >> 6) & 511u], 1u);
            vals[e0 + p] = w;
        }
    }
}

// ---------------- layer-1 pull aggregate: fp8 table, f32 accumulate --------
// wave per node; lanes = 8 edge-slots x 8 feature-pairs. Each lane fetches
// 4 B (features 2q,2q+1 x both knots, fp8) from the L2-resident 3.2 MB table.
__global__ __launch_bounds__(256) void k_agg1(
    const uint* __restrict__ rowptr, const uint* __restrict__ vals,
    const uint* __restrict__ hp8, float2* __restrict__ sum1)
{
    __shared__ uint2 ent[4][64];        // 2 KB: per-wave {src, u_bits}
    const int tid = threadIdx.x;
    const int lane = tid & 63;
    const int wave = tid >> 6;
    const int n = blockIdx.x * 4 + wave;
    const int ep = lane >> 3;          // edge slot 0..7
    const int q  = lane & 7;           // feature pair: features 2q, 2q+1

    const uint r0 = rowptr[n];
    const uint deg = rowptr[n + 1] - r0;
    const uint dcap = min(deg, 64u);

    if ((uint)lane < dcap) {
        const uint v = __builtin_nontemporal_load(&vals[r0 + lane]);
        const float uu = (float)(v & 63u) * (1.0f / 63.0f);
        ent[wave][lane] = make_uint2(v >> 15, __float_as_uint(uu));
    }
    __syncthreads();

    float acc_a = 0.f, acc_b = 0.f;
    #pragma unroll 4
    for (uint i = ep; i < dcap; i += 8) {
        const uint2 e = ent[wave][i];
        const float u = __uint_as_float(e.y);
        const float w0 = 1.0f - u;
        __hip_fp8x4_e4m3 p;
        p.__x = (__hip_fp8x4_storage_t)hp8[(size_t)e.x * 8 + q];
        const float4 h = (float4)p;          // (h0_2q, h1_2q, h0_2q+1, h1_2q+1)
        acc_a += w0 * h.x + u * h.y;
        acc_b += w0 * h.z + u * h.w;
    }
    for (uint i = 64 + ep; i < deg; i += 8) {    // rare overflow tail
        const uint v = __builtin_nontemporal_load(&vals[r0 + i]);
        const float u = (float)(v & 63u) * (1.0f / 63.0f);
        const float w0 = 1.0f - u;
        __hip_fp8x4_e4m3 p;
        p.__x = (__hip_fp8x4_storage_t)hp8[(size_t)(v >> 15) * 8 + q];
        const float4 h = (float4)p;
        acc_a += w0 * h.x + u * h.y;
        acc_b += w0 * h.z + u * h.w;
    }
    acc_a += __shfl_xor(acc_a, 8); acc_a += __shfl_xor(acc_a, 16); acc_a += __shfl_xor(acc_a, 32);
    acc_b += __shfl_xor(acc_b, 8); acc_b += __shfl_xor(acc_b, 16); acc_b += __shfl_xor(acc_b, 32);

    if (lane < 8)
        sum1[(size_t)n * 8 + lane] = make_float2(acc_a, acc_b);
}

// ---------------- dense per-node finalize: mean + ELU + layer-2 transforms -
__global__ __launch_bounds__(256) void k_mid2(
    const float2* __restrict__ sum1, const uint* __restrict__ rowptr,
    const float* __restrict__ r1,
    const float* __restrict__ W2, const float* __restrict__ root2,
    const float* __restrict__ b2,
    float4* __restrict__ h2, float2* __restrict__ r2)
{
    __shared__ float w2s[2 * F_HID * F_OUT];
    __shared__ float rts[F_HID * F_OUT];
    __shared__ float b2s[F_OUT];
    const int tid = threadIdx.x;
    if (tid < 2 * F_HID * F_OUT) w2s[tid] = W2[tid];
    if (tid < F_HID * F_OUT)     rts[tid] = root2[tid];
    if (tid < F_OUT)             b2s[tid] = b2[tid];
    __syncthreads();

    const int n = blockIdx.x * 256 + tid;
    if (n >= N_NODES) return;

    const uint deg = rowptr[n + 1] - rowptr[n];
    const float inv = 1.0f / (float)max(deg, 1u);

    float h[F_HID];
    #pragma unroll
    for (int k = 0; k < 8; ++k) {
        const float2 s = sum1[(size_t)n * 8 + k];
        const float v0 = s.x * inv + r1[(size_t)n * F_HID + 2 * k];
        const float v1 = s.y * inv + r1[(size_t)n * F_HID + 2 * k + 1];
        h[2 * k]     = (v0 > 0.0f) ? v0 : expm1f(v0);   // ELU
        h[2 * k + 1] = (v1 > 0.0f) ? v1 : expm1f(v1);
    }
    float o00 = 0.f, o01 = 0.f, o10 = 0.f, o11 = 0.f;
    float rr0 = b2s[0], rr1 = b2s[1];
    #pragma unroll
    for (int f = 0; f < F_HID; ++f) {
        o00 = fmaf(h[f], w2s[f * 2 + 0], o00);
        o01 = fmaf(h[f], w2s[f * 2 + 1], o01);
        o10 = fmaf(h[f], w2s[2 * F_HID + f * 2 + 0], o10);
        o11 = fmaf(h[f], w2s[2 * F_HID + f * 2 + 1], o11);
        rr0 = fmaf(h[f], rts[f * 2 + 0], rr0);
        rr1 = fmaf(h[f], rts[f * 2 + 1], rr1);
    }
    h2[n] = make_float4(o00, o10, o01, o11);   // (k0o0, k1o0, k0o1, k1o1)
    r2[n] = make_float2(rr0, rr1);
}

// ---------------- layer-2 pull aggregate + log_softmax --------------------
// 2 nodes per wave; 1 lane per edge; no LDS.
__global__ __launch_bounds__(256) void k_agg2(
    const uint* __restrict__ rowptr, const uint* __restrict__ vals,
    const float4* __restrict__ h2, const float2* __restrict__ r2,
    float2* __restrict__ out)
{
    const int tid  = threadIdx.x;
    const int lane = tid & 63;
    const int wave = tid >> 6;
    const int half = lane & 31;
    const int n = blockIdx.x * 8 + wave * 2 + (lane >> 5);

    const uint r0 = rowptr[n];
    const uint deg = rowptr[n + 1] - r0;

    float acc0 = 0.f, acc1 = 0.f;
    for (uint i = half; i < deg; i += 32) {
        const uint v = __builtin_nontemporal_load(&vals[r0 + i]);
        const float uu = (float)(v & 63u) * (1.0f / 63.0f);
        const float4 h = h2[v >> 15];
        acc0 += (1.0f - uu) * h.x + uu * h.y;   // out0: (1-u)*k0 + u*k1
        acc1 += (1.0f - uu) * h.z + uu * h.w;   // out1
    }
    #pragma unroll
    for (int off = 1; off <= 16; off <<= 1) {
        acc0 += __shfl_xor(acc0, off);
        acc1 += __shfl_xor(acc1, off);
    }

    if (half == 0) {
        const float inv = 1.0f / (float)max(deg, 1u);
        const float2 rr = r2[n];
        const float o0 = acc0 * inv + rr.x;
        const float o1 = acc1 * inv + rr.y;
        const float m  = fmaxf(o0, o1);
        const float l  = m + logf(expf(o0 - m) + expf(o1 - m));
        out[n] = make_float2(o0 - l, o1 - l);
    }
}

extern "C" void kernel_launch(void* const* d_in, const int* in_sizes, int n_in,
                              void* d_out, int out_size, void* d_ws, size_t ws_size,
                              hipStream_t stream) {
    const float* x     = (const float*)d_in[0];
    const int*   ei    = (const int*)  d_in[1];   // [2][N_EDGES]
    const float* attr  = (const float*)d_in[2];
    const float* W1    = (const float*)d_in[4];
    const float* root1 = (const float*)d_in[5];
    const float* b1    = (const float*)d_in[6];
    const float* W2    = (const float*)d_in[7];
    const float* root2 = (const float*)d_in[8];
    const float* b2    = (const float*)d_in[9];
    float2* out = (float2*)d_out;

    char* ws = (char*)d_ws;
    size_t off = 0;
    uint*  vals   = (uint*) (ws + off); off += (size_t)N_EDGES * sizeof(uint);         // 12.8MB
    uint*  rowptr = (uint*) (ws + off); off += (size_t)(N_NODES + 1) * sizeof(uint);
    uint*  cnt    = (uint*) (ws + off); off += (size_t)NBUCK * HB * sizeof(uint);      // 200KB
    uint*  bstart = (uint*) (ws + off); off += (size_t)(NBUCK + 1) * sizeof(uint);
    uint*  tot    = (uint*) (ws + off); off += (size_t)NBUCK * sizeof(uint);
    off = (off + 255) & ~(size_t)255;
    uint*  buck   = (uint*) (ws + off); off += (size_t)N_EDGES * sizeof(uint);         // 12.8MB

    // buck is dead after k_fscatter; node buffers alias from buck onward.
    char* alias = (char*)buck;
    size_t aoff = 0;
    uint2*  hp8 = (uint2*) (alias + aoff); aoff += (size_t)N_NODES * 4 * sizeof(uint2);       // 3.2MB
    float*   r1 = (float*) (alias + aoff); aoff += (size_t)N_NODES * F_HID * sizeof(float);   // 6.4MB
    float4*  h2 = (float4*)(alias + aoff); aoff += (size_t)N_NODES * sizeof(float4);          // 1.6MB
    float2*  r2 = (float2*)(alias + aoff); aoff += (size_t)N_NODES * sizeof(float2);          // 0.8MB
    float2* sum1= (float2*)(alias + aoff); aoff += (size_t)N_NODES * 8 * sizeof(float2);      // 6.4MB
    (void)ws_size;

    const int* esrc = ei;
    const int* edst = ei + N_EDGES;

    k_bhist    <<<HB, 1024, 0, stream>>>(edst, cnt);
    k_brow1    <<<NBUCK, 256, 0, stream>>>(cnt, tot);
    k_bexc     <<<1, 256, 0, stream>>>(tot, bstart);
    k_bscatter <<<HB, 1024, 0, stream>>>(esrc, edst, attr, cnt, bstart, buck);
    k_fscatter <<<NBUCK, 1024, 0, stream>>>(buck, bstart, rowptr, vals);
    k_transform1<<<(N_NODES * 4 + 255) / 256, 256, 0, stream>>>(x, W1, root1, b1, hp8, r1);
    k_agg1     <<<N_NODES / 4, 256, 0, stream>>>(rowptr, vals, (const uint*)hp8, sum1);
    k_mid2     <<<(N_NODES + 255) / 256, 256, 0, stream>>>(sum1, rowptr, r1, W2, root2, b2, h2, r2);
    k_agg2     <<<N_NODES / 8, 256, 0, stream>>>(rowptr, vals, h2, r2, out);
}